// Round 5
// baseline (280.359 us; speedup 1.0000x reference)
//
#include <hip/hip_runtime.h>

// Problem constants (match reference)
#define C 80
#define P 30000
#define G 800
#define BS 256
#define NB 16          // 64-px cells over [0,1024); boxes binned by CENTER
#define NC (NB * NB)   // 256 cells per class
#define PPT 8          // preds per thread in match
#define TPB (BS * PPT) // 2048 preds per match block (block-local sort granule)

// Center-binning prune (validated absmax 0.0 across rounds 1-4): IoU > 0.5
// forces each box to contain the other's center in both dims -> |dc| < 64
// px/dim -> all viable pairs lie in the 3x3 neighborhood of the pred's 64-px
// center cell. Pruned pairs provably have IoU <= 0.5; validity re-verified
// with the bit-exact reference division in the epilogue.
//
// Round-5: (1) GT staged as float4+e -> inner iter = 1 ds_read_b128 +
// 1 ds_read_b32 + ONE addr calc (was 5 b32 + 5 addr calcs; round-4 VALU
// issue was ~5x the pair math). (2) sortc+hist+ap2m fused into one
// finale_kernel (keys never leave LDS; scores read from L3-hot pred) —
// 5 launches -> 3.

// rank order = score desc, then pred-index asc. Packed key is monotone in
// that order (scores >= 0 so float bits are order-preserving). key==0 means
// "no match" (needs score==0.0f AND p==P-1 — probability ~0).
__device__ __forceinline__ unsigned long long pack_key(float s, int p) {
    return ((unsigned long long)__float_as_uint(s) << 32) | (unsigned)(P - 1 - p);
}

__device__ __forceinline__ int cell_of_center(float cxf, float cyf) {
    int bx = min(max((int)(cxf * (1.0f / 64.0f)), 0), NB - 1);
    int by = min(max((int)(cyf * (1.0f / 64.0f)), 0), NB - 1);
    return by * NB + bx;
}

// ---------------- gt binning: one block per class (count+scan+scatter) ------
// BS == NC == 256: thread t owns cell t. Also zeroes this class's gtKey and
// the finale ticket counter (init kernel folded in).
__global__ __launch_bounds__(BS) void gt_bin_kernel(
        const float* __restrict__ gt,
        unsigned short* __restrict__ gtCnt, unsigned short* __restrict__ gtOff,
        float4* __restrict__ gtBox, float* __restrict__ gtAbe,
        unsigned short* __restrict__ gtIdx,
        unsigned long long* __restrict__ gtKey,
        unsigned int* __restrict__ doneCnt) {
    __shared__ int h[NC], cur[NC];
    __shared__ int gcell[G];
    const int c = blockIdx.x, tid = threadIdx.x;
    h[tid] = 0;
    if (c == 0 && tid == 0) *doneCnt = 0u;                           // folded init
    for (int i = tid; i < G; i += BS) gtKey[c * G + i] = 0ull;       // folded init
    __syncthreads();
    for (int i = tid; i < G; i += BS) {
        const float* r = gt + ((size_t)c * G + i) * 7;
        int cl = cell_of_center(0.5f * (r[3] + r[5]), 0.5f * (r[4] + r[6]));
        gcell[i] = cl;
        atomicAdd(&h[cl], 1);
    }
    __syncthreads();
    const int v = h[tid];
    cur[tid] = v;
    __syncthreads();
    for (int o = 1; o < NC; o <<= 1) {   // inclusive scan, 8 steps
        int t = (tid >= o) ? cur[tid - o] : 0;
        __syncthreads();
        cur[tid] += t;
        __syncthreads();
    }
    const int excl = cur[tid] - v;
    gtOff[c * NC + tid] = (unsigned short)excl;
    gtCnt[c * NC + tid] = (unsigned short)v;
    __syncthreads();
    cur[tid] = excl;
    __syncthreads();
    for (int i = tid; i < G; i += BS) {
        const float* r = gt + ((size_t)c * G + i) * 7;   // L1-hot (2nd pass)
        float x1 = r[3], y1 = r[4], x2 = r[5], y2 = r[6];
        int slot = atomicAdd(&cur[gcell[i]], 1);
        gtBox[c * G + slot] = make_float4(x1, y1, x2, y2);
        // area + eps pre-folded: cross-compare uses sb = A + (area_g + eps);
        // the -inter terms of the two denominators cancel algebraically.
        gtAbe[c * G + slot] = __fadd_rn(__fmul_rn(__fsub_rn(x2, x1), __fsub_rn(y2, y1)), 1e-9f);
        gtIdx[c * G + slot] = (unsigned short)i;
    }
}

// ---------------- match: streamed preds + block-local cell sort ----------
// Phase A: coalesced pass over the block's 2048 preds -> cell + LDS hist.
// Scan (proven 256-bin pattern) -> exclusive base. Scatter local indices into
// sorted order. Phase B: process preds in cell-sorted order — wave covers ~8
// cells -> broadcast-group LDS reads; GT box is ONE ds_read_b128 (+b32 for e)
// with immediate-offset unrolling. Pair arithmetic, GT order, and epilogue
// bit-identical to proven rounds 2-4; processing order irrelevant (atomicMax).
__global__ __launch_bounds__(BS) void match7_kernel(
        const float* __restrict__ pred,
        const unsigned short* __restrict__ gtOff, const unsigned short* __restrict__ gtCnt,
        const float4* __restrict__ gtBox, const float* __restrict__ gtAbe,
        const unsigned short* __restrict__ gtIdx,
        unsigned long long* __restrict__ gtKey) {
    __shared__ float4 sB[G];                        // 12.8 KB
    __shared__ float  sE[G];                        //  3.2 KB
    __shared__ unsigned short sG[G];                //  1.6 KB
    __shared__ unsigned short sOff[NC], sCnt[NC];   //  1.0 KB
    __shared__ unsigned short sIdx[TPB];            //  4.0 KB
    __shared__ int hcnt[NC], bb[NC];                //  2.0 KB
    const int c = blockIdx.y, tid = threadIdx.x;
    const int p0 = blockIdx.x * TPB;
    const int cntP = min(TPB, P - p0);

    for (int i = tid; i < G; i += BS) {
        sB[i] = gtBox[c * G + i];
        sE[i] = gtAbe[c * G + i];
        sG[i] = gtIdx[c * G + i];
    }
    sOff[tid] = gtOff[c * NC + tid];   // BS == NC
    sCnt[tid] = gtCnt[c * NC + tid];
    hcnt[tid] = 0;
    __syncthreads();

    const size_t cp = (size_t)c * P;

    // ---- phase A: coalesced cell computation + block histogram ----
    unsigned char  cellA[PPT];
    unsigned short lrA[PPT];
    #pragma unroll
    for (int rep = 0; rep < PPT; ++rep) {
        const int li = rep * BS + tid;
        const int p  = p0 + li;
        int cell = 0, lr = 0;
        if (p < P) {
            const float* r = pred + (cp + p) * 7;
            cell = cell_of_center(0.5f * (r[3] + r[5]), 0.5f * (r[4] + r[6]));
            lr = atomicAdd(&hcnt[cell], 1);
        }
        cellA[rep] = (unsigned char)cell;
        lrA[rep] = (unsigned short)lr;
    }
    __syncthreads();

    // ---- scan 256 bins (proven pattern) -> exclusive base in bb ----
    const int v = hcnt[tid];
    __syncthreads();
    for (int o = 1; o < NC; o <<= 1) {
        int t = (tid >= o) ? hcnt[tid - o] : 0;
        __syncthreads();
        hcnt[tid] += t;
        __syncthreads();
    }
    bb[tid] = hcnt[tid] - v;
    __syncthreads();

    // ---- scatter local indices into cell-sorted order ----
    #pragma unroll
    for (int rep = 0; rep < PPT; ++rep) {
        const int li = rep * BS + tid;
        if (p0 + li < P) sIdx[bb[cellA[rep]] + lrA[rep]] = (unsigned short)li;
    }
    __syncthreads();

    // ---- phase B: pair loop in sorted order ----
    #pragma unroll 1
    for (int rep = 0; rep < PPT; ++rep) {
        const int si = rep * BS + tid;
        if (si < cntP) {
            const int li = sIdx[si];
            const int p  = p0 + li;
            const float* r = pred + (cp + p) * 7;     // L2/L3 re-gather
            float ax1 = r[3], ay1 = r[4], ax2 = r[5], ay2 = r[6];
            float A = __fmul_rn(__fsub_rn(ax2, ax1), __fsub_rn(ay2, ay1));
            // recompute cell from the box (deterministic == phase A's value)
            const int cell = cell_of_center(0.5f * (ax1 + ax2), 0.5f * (ay1 + ay2));
            const int cx = cell & (NB - 1), cy = cell >> 4;
            const int x0 = max(cx - 1, 0), x1 = min(cx + 1, NB - 1);
            const int y0 = max(cy - 1, 0), y1 = min(cy + 1, NB - 1);
            float IN = 0.0f, SB = 1.0f;
            int mj = -1;
            for (int yy = y0; yy <= y1; ++yy) {
                const int rowb = yy * NB;
                const int jb = sOff[rowb + x0];
                const int je = sOff[rowb + x1] + sCnt[rowb + x1];
                #pragma unroll 2
                for (int j = jb; j < je; ++j) {
                    float4 b = sB[j];
                    float lx = fmaxf(ax1, b.x), ly = fmaxf(ay1, b.y);
                    float rx = fminf(ax2, b.z), ry = fminf(ay2, b.w);
                    float wx = fmaxf(__fsub_rn(rx, lx), 0.0f);
                    float wy = fmaxf(__fsub_rn(ry, ly), 0.0f);
                    float in = __fmul_rn(wx, wy);
                    float sb = __fadd_rn(A, sE[j]);
                    bool  up = __fmul_rn(in, SB) > __fmul_rn(IN, sb);
                    IN = up ? in : IN; SB = up ? sb : SB; mj = up ? j : mj;
                }
            }
            if (IN > 0.0f) {   // zero-inter preds can never be valid
                float4 b = sB[mj];
                float area = __fmul_rn(__fsub_rn(b.z, b.x), __fsub_rn(b.w, b.y));
                float dn = __fadd_rn(__fsub_rn(__fadd_rn(A, area), IN), 1e-9f);
                float iou = __fdiv_rn(IN, dn);   // exact reference value
                if (iou > 0.5f) {
                    float sscore = r[2];         // rare path
                    atomicMax(&gtKey[c * G + sG[mj]], pack_key(sscore, p));
                }
            }
        }
    }
}

// ---------------- finale: compact+sort+hist+prefix+AP+mean, 1 block/class --
// Fuses the proven sortc / hist / ap2m kernels; sorted keys stay in LDS,
// scores come straight from pred (identical bits to the old scoreC staging;
// pred slab is L3-resident). Arithmetic verbatim from rounds 1-4.
__global__ __launch_bounds__(BS) void finale_kernel(
        const float* __restrict__ pred,
        const unsigned long long* __restrict__ gtKey,
        float* __restrict__ ap, unsigned int* __restrict__ doneCnt,
        float* __restrict__ out) {
    __shared__ unsigned long long k[G];     // 6.4 KB compacted keys
    __shared__ unsigned long long sk[1024]; // 8 KB sorted-desc keys (pad=0)
    __shared__ int h[1024];                 // 4 KB histogram / scan ping
    __shared__ int hb[1024];                // 4 KB scan pong
    __shared__ float red[BS];
    __shared__ int cnt;
    const int c = blockIdx.x, tid = threadIdx.x;

    // ---- compact nonzero gtKey ----
    if (tid == 0) cnt = 0;
    for (int j = tid; j < 1024; j += BS) { sk[j] = 0ull; h[j] = 0; }
    __syncthreads();
    for (int i = tid; i < G; i += BS) {
        unsigned long long key = gtKey[c * G + i];
        if (key != 0ull) k[atomicAdd(&cnt, 1)] = key;
    }
    __syncthreads();
    const int T = cnt;

    // ---- O(T^2) broadcast position-sort (keys unique) ----
    for (int t = tid; t < T; t += BS) {
        unsigned long long key = k[t];
        int pos = 0;
        for (int u = 0; u < T; ++u) pos += (k[u] > key) ? 1 : 0;
        sk[pos] = key;
    }
    __syncthreads();

    // ---- hist: pos(q) for every pred via binary search ----
    const float* pr = pred + (size_t)c * P * 7;
    for (int i = tid; i < P; i += BS) {
        unsigned long long kq =
            ((unsigned long long)__float_as_uint(pr[(size_t)i * 7 + 2]) << 32)
            | (unsigned)(P - 1 - i);
        int lo = 0;   // count of sorted-desc keys > kq (pads are 0, never > kq)
        #pragma unroll
        for (int step = 512; step > 0; step >>= 1)
            if (sk[lo + step - 1] > kq) lo += step;
        atomicAdd(&h[lo], 1);
    }
    __syncthreads();

    // ---- inclusive prefix over h (ping-pong, verbatim ap2 pattern) ----
    int* src = h; int* dst = hb;
    for (int o = 1; o < 1024; o <<= 1) {
        for (int j = tid; j < 1024; j += BS)
            dst[j] = src[j] + ((j >= o) ? src[j - o] : 0);
        __syncthreads();
        int* tmp = src; src = dst; dst = tmp;
    }

    // ---- AP closed-form terms ----
    float sum = 0.0f;
    for (int s = tid; s < T; s += BS) {
        int r = src[s] - 1;          // inclusive prefix minus self
        if (r >= 1) {
            float kf  = (float)(s + 1);
            float km  = (float)s;
            float ri  = __fdiv_rn(kf, 800.0f);
            float rim = __fdiv_rn(km, 800.0f);
            float pi  = __fdiv_rn(kf, (float)(r + 1));
            float pim = __fdiv_rn(km, (float)r);
            sum = __fadd_rn(sum,
                  __fmul_rn(__fmul_rn(__fsub_rn(ri, rim), __fadd_rn(pi, pim)), 0.5f));
        }
    }
    red[tid] = sum;
    __syncthreads();
    for (int s2 = BS / 2; s2 > 0; s2 >>= 1) {
        if (tid < s2) red[tid] = __fadd_rn(red[tid], red[tid + s2]);
        __syncthreads();
    }
    if (tid == 0) {
        ap[c] = red[0];
        __threadfence();                         // publish ap[c] device-wide
        unsigned int t = atomicAdd(doneCnt, 1u); // ticket
        if (t == C - 1) {                        // last block finishes the mean
            __threadfence();                     // acquire all ap[] writes
            float s = 0.0f;
            for (int c2 = 0; c2 < C; ++c2) s = __fadd_rn(s, ap[c2]);
            out[0] = __fdiv_rn(s, 80.0f);
        }
    }
}

extern "C" void kernel_launch(void* const* d_in, const int* in_sizes, int n_in,
                              void* d_out, int out_size, void* d_ws, size_t ws_size,
                              hipStream_t stream) {
    const float* pred = (const float*)d_in[0];   // [C, P, 7] f32
    const float* gt   = (const float*)d_in[1];   // [C, G, 7] f32
    float* out = (float*)d_out;

    // Workspace layout — 2,002,944 B total (sortedKeys/gHist/sortT gone with
    // the finale fusion). Re-poisoned 0xAA each call — gt_bin (incl. folded
    // inits: gtKey, doneCnt) rewrites everything read-before-write; finale's
    // k/sk/h live entirely in LDS.
    char* ws = (char*)d_ws;
    float*              ap         = (float*)             (ws + 0);         //     320 B
    unsigned int*       doneCnt    = (unsigned int*)      (ws + 512);       //       4 B
    unsigned short*     gtCnt      = (unsigned short*)    (ws + 1024);      //  40960 B
    unsigned short*     gtOff      = (unsigned short*)    (ws + 41984);     //  40960 B
    unsigned short*     gtIdx      = (unsigned short*)    (ws + 82944);     // 128000 B
    float*              gtAbe      = (float*)             (ws + 210944);    // 256000 B
    float4*             gtBox      = (float4*)            (ws + 466944);    // 1.024 MB (16-aligned)
    unsigned long long* gtKey      = (unsigned long long*)(ws + 1490944);   // 512000 B
    // end: 2002944 B

    const int M_BLK = (P + TPB - 1) / TPB;   // 15

    gt_bin_kernel<<<C, BS, 0, stream>>>(gt, gtCnt, gtOff, gtBox, gtAbe, gtIdx,
                                        gtKey, doneCnt);
    match7_kernel<<<dim3(M_BLK, C), BS, 0, stream>>>(pred, gtOff, gtCnt, gtBox,
                                                     gtAbe, gtIdx, gtKey);
    finale_kernel<<<C, BS, 0, stream>>>(pred, gtKey, ap, doneCnt, out);
}

// Round 7
// 226.720 us; speedup vs baseline: 1.2366x; 1.2366x over previous
//
#include <hip/hip_runtime.h>

// Problem constants (match reference)
#define C 80
#define P 30000
#define G 800
#define BS 256
#define NB 16          // 64-px cells over [0,1024); boxes binned by CENTER
#define NC (NB * NB)   // 256 cells per class
#define PPT 8          // preds per thread in match
#define TPB (BS * PPT) // 2048 preds per match block (block-local sort granule)
#define HCH 8          // hist chunks per class (finale parallelism)
#define CHSZ ((P + HCH - 1) / HCH)   // 3750

// Center-binning prune (validated absmax 0.0 across rounds 1-5): IoU > 0.5
// forces each box to contain the other's center in both dims -> |dc| < 64
// px/dim -> all viable pairs lie in the 3x3 neighborhood of the pred's 64-px
// center cell. Pruned pairs provably have IoU <= 0.5; validity re-verified
// with the bit-exact reference division in the epilogue.
//
// Round-7: round-6 FAILED (absmax 0.074) because the per-class ticket block
// read gHist with plain loads after __threadfence() — cross-XCD L2s are not
// coherent, stale bins were served (Guideline 16). Fix: split at that edge.
// Same parallel decomposition (640-block finale stage), but gHist crosses a
// KERNEL BOUNDARY before being consumed: histf (compact+sort redundant x8 +
// chunked hist -> gHist atomics) then ap2m (round-4-verbatim prefix+AP+
// ticket-mean, which passed absmax 0.0). 4 launches.

// rank order = score desc, then pred-index asc. Packed key is monotone in
// that order (scores >= 0 so float bits are order-preserving). key==0 means
// "no match" (needs score==0.0f AND p==P-1 — probability ~0).
__device__ __forceinline__ unsigned long long pack_key(float s, int p) {
    return ((unsigned long long)__float_as_uint(s) << 32) | (unsigned)(P - 1 - p);
}

__device__ __forceinline__ int cell_of_center(float cxf, float cyf) {
    int bx = min(max((int)(cxf * (1.0f / 64.0f)), 0), NB - 1);
    int by = min(max((int)(cyf * (1.0f / 64.0f)), 0), NB - 1);
    return by * NB + bx;
}

// ---------------- gt binning: one block per class (count+scan+scatter) ------
// BS == NC == 256: thread t owns cell t. Also zeroes this class's gtKey,
// gHist slab, and the global ticket (init folded in).
__global__ __launch_bounds__(BS) void gt_bin_kernel(
        const float* __restrict__ gt,
        unsigned short* __restrict__ gtCnt, unsigned short* __restrict__ gtOff,
        float4* __restrict__ gtBox, float* __restrict__ gtAbe,
        unsigned short* __restrict__ gtIdx,
        unsigned long long* __restrict__ gtKey, int* __restrict__ gHist,
        unsigned int* __restrict__ doneCnt) {
    __shared__ int h[NC], cur[NC];
    __shared__ int gcell[G];
    const int c = blockIdx.x, tid = threadIdx.x;
    h[tid] = 0;
    if (c == 0 && tid == 0) *doneCnt = 0u;                           // folded init
    for (int i = tid; i < G; i += BS) gtKey[c * G + i] = 0ull;       // folded init
    for (int j = tid; j < 1024; j += BS) gHist[c * 1024 + j] = 0;    // folded init
    __syncthreads();
    for (int i = tid; i < G; i += BS) {
        const float* r = gt + ((size_t)c * G + i) * 7;
        int cl = cell_of_center(0.5f * (r[3] + r[5]), 0.5f * (r[4] + r[6]));
        gcell[i] = cl;
        atomicAdd(&h[cl], 1);
    }
    __syncthreads();
    const int v = h[tid];
    cur[tid] = v;
    __syncthreads();
    for (int o = 1; o < NC; o <<= 1) {   // inclusive scan, 8 steps
        int t = (tid >= o) ? cur[tid - o] : 0;
        __syncthreads();
        cur[tid] += t;
        __syncthreads();
    }
    const int excl = cur[tid] - v;
    gtOff[c * NC + tid] = (unsigned short)excl;
    gtCnt[c * NC + tid] = (unsigned short)v;
    __syncthreads();
    cur[tid] = excl;
    __syncthreads();
    for (int i = tid; i < G; i += BS) {
        const float* r = gt + ((size_t)c * G + i) * 7;   // L1-hot (2nd pass)
        float x1 = r[3], y1 = r[4], x2 = r[5], y2 = r[6];
        int slot = atomicAdd(&cur[gcell[i]], 1);
        gtBox[c * G + slot] = make_float4(x1, y1, x2, y2);
        // area + eps pre-folded: cross-compare uses sb = A + (area_g + eps);
        // the -inter terms of the two denominators cancel algebraically.
        gtAbe[c * G + slot] = __fadd_rn(__fmul_rn(__fsub_rn(x2, x1), __fsub_rn(y2, y1)), 1e-9f);
        gtIdx[c * G + slot] = (unsigned short)i;
    }
}

// ---------------- match: streamed preds + block-local cell sort ----------
// (verbatim from round 5 — passed absmax 0.0.) Phase A: coalesced cell pass +
// LDS hist; 256-bin scan; scatter local indices into cell-sorted order.
// Phase B: pair loop in sorted order — wave covers ~8 cells -> broadcast-
// group LDS reads; GT box is ONE ds_read_b128 (+b32 for e). Pair arithmetic,
// GT order, epilogue bit-identical to proven rounds 2-5.
__global__ __launch_bounds__(BS) void match7_kernel(
        const float* __restrict__ pred,
        const unsigned short* __restrict__ gtOff, const unsigned short* __restrict__ gtCnt,
        const float4* __restrict__ gtBox, const float* __restrict__ gtAbe,
        const unsigned short* __restrict__ gtIdx,
        unsigned long long* __restrict__ gtKey) {
    __shared__ float4 sB[G];                        // 12.8 KB
    __shared__ float  sE[G];                        //  3.2 KB
    __shared__ unsigned short sG[G];                //  1.6 KB
    __shared__ unsigned short sOff[NC], sCnt[NC];   //  1.0 KB
    __shared__ unsigned short sIdx[TPB];            //  4.0 KB
    __shared__ int hcnt[NC], bb[NC];                //  2.0 KB
    const int c = blockIdx.y, tid = threadIdx.x;
    const int p0 = blockIdx.x * TPB;
    const int cntP = min(TPB, P - p0);

    for (int i = tid; i < G; i += BS) {
        sB[i] = gtBox[c * G + i];
        sE[i] = gtAbe[c * G + i];
        sG[i] = gtIdx[c * G + i];
    }
    sOff[tid] = gtOff[c * NC + tid];   // BS == NC
    sCnt[tid] = gtCnt[c * NC + tid];
    hcnt[tid] = 0;
    __syncthreads();

    const size_t cp = (size_t)c * P;

    // ---- phase A: coalesced cell computation + block histogram ----
    unsigned char  cellA[PPT];
    unsigned short lrA[PPT];
    #pragma unroll
    for (int rep = 0; rep < PPT; ++rep) {
        const int li = rep * BS + tid;
        const int p  = p0 + li;
        int cell = 0, lr = 0;
        if (p < P) {
            const float* r = pred + (cp + p) * 7;
            cell = cell_of_center(0.5f * (r[3] + r[5]), 0.5f * (r[4] + r[6]));
            lr = atomicAdd(&hcnt[cell], 1);
        }
        cellA[rep] = (unsigned char)cell;
        lrA[rep] = (unsigned short)lr;
    }
    __syncthreads();

    // ---- scan 256 bins (proven pattern) -> exclusive base in bb ----
    const int v = hcnt[tid];
    __syncthreads();
    for (int o = 1; o < NC; o <<= 1) {
        int t = (tid >= o) ? hcnt[tid - o] : 0;
        __syncthreads();
        hcnt[tid] += t;
        __syncthreads();
    }
    bb[tid] = hcnt[tid] - v;
    __syncthreads();

    // ---- scatter local indices into cell-sorted order ----
    #pragma unroll
    for (int rep = 0; rep < PPT; ++rep) {
        const int li = rep * BS + tid;
        if (p0 + li < P) sIdx[bb[cellA[rep]] + lrA[rep]] = (unsigned short)li;
    }
    __syncthreads();

    // ---- phase B: pair loop in sorted order ----
    #pragma unroll 1
    for (int rep = 0; rep < PPT; ++rep) {
        const int si = rep * BS + tid;
        if (si < cntP) {
            const int li = sIdx[si];
            const int p  = p0 + li;
            const float* r = pred + (cp + p) * 7;     // L2/L3 re-gather
            float ax1 = r[3], ay1 = r[4], ax2 = r[5], ay2 = r[6];
            float A = __fmul_rn(__fsub_rn(ax2, ax1), __fsub_rn(ay2, ay1));
            // recompute cell from the box (deterministic == phase A's value)
            const int cell = cell_of_center(0.5f * (ax1 + ax2), 0.5f * (ay1 + ay2));
            const int cx = cell & (NB - 1), cy = cell >> 4;
            const int x0 = max(cx - 1, 0), x1 = min(cx + 1, NB - 1);
            const int y0 = max(cy - 1, 0), y1 = min(cy + 1, NB - 1);
            float IN = 0.0f, SB = 1.0f;
            int mj = -1;
            for (int yy = y0; yy <= y1; ++yy) {
                const int rowb = yy * NB;
                const int jb = sOff[rowb + x0];
                const int je = sOff[rowb + x1] + sCnt[rowb + x1];
                #pragma unroll 2
                for (int j = jb; j < je; ++j) {
                    float4 b = sB[j];
                    float lx = fmaxf(ax1, b.x), ly = fmaxf(ay1, b.y);
                    float rx = fminf(ax2, b.z), ry = fminf(ay2, b.w);
                    float wx = fmaxf(__fsub_rn(rx, lx), 0.0f);
                    float wy = fmaxf(__fsub_rn(ry, ly), 0.0f);
                    float in = __fmul_rn(wx, wy);
                    float sb = __fadd_rn(A, sE[j]);
                    bool  up = __fmul_rn(in, SB) > __fmul_rn(IN, sb);
                    IN = up ? in : IN; SB = up ? sb : SB; mj = up ? j : mj;
                }
            }
            if (IN > 0.0f) {   // zero-inter preds can never be valid
                float4 b = sB[mj];
                float area = __fmul_rn(__fsub_rn(b.z, b.x), __fsub_rn(b.w, b.y));
                float dn = __fadd_rn(__fsub_rn(__fadd_rn(A, area), IN), 1e-9f);
                float iou = __fdiv_rn(IN, dn);   // exact reference value
                if (iou > 0.5f) {
                    float sscore = r[2];         // rare path
                    atomicMax(&gtKey[c * G + sG[mj]], pack_key(sscore, p));
                }
            }
        }
    }
}

// ---------------- histf: compact+sort (x8 redundant) + chunked hist ------
// dim3(HCH, C) = 640 blocks. Sort is deterministic (keys unique -> position
// sort independent of compaction order), so all 8 blocks of a class derive
// the same sk[]. Each block histograms its own 3750-pred chunk (round-4 hist,
// verbatim) into global gHist via atomics; chunk 0 also records sortT[c].
// gHist is CONSUMED ONLY IN THE NEXT LAUNCH (round-6 lesson: no intra-kernel
// cross-block plain reads of atomically-written data on non-coherent XCDs).
__global__ __launch_bounds__(BS) void histf_kernel(
        const float* __restrict__ pred,
        const unsigned long long* __restrict__ gtKey,
        int* __restrict__ gHist, int* __restrict__ sortT) {
    __shared__ unsigned long long k[G];     // 6.4 KB compacted keys
    __shared__ unsigned long long sk[1024]; // 8 KB sorted-desc keys (pad=0)
    __shared__ int h[1024];                 // 4 KB local hist
    __shared__ int cnt;
    const int c = blockIdx.y, chunk = blockIdx.x, tid = threadIdx.x;

    // ---- compact nonzero gtKey (redundant per chunk; deterministic) ----
    if (tid == 0) cnt = 0;
    for (int j = tid; j < 1024; j += BS) { sk[j] = 0ull; h[j] = 0; }
    __syncthreads();
    for (int i = tid; i < G; i += BS) {
        unsigned long long key = gtKey[c * G + i];
        if (key != 0ull) k[atomicAdd(&cnt, 1)] = key;
    }
    __syncthreads();
    const int T = cnt;
    if (chunk == 0 && tid == 0) sortT[c] = T;

    // ---- O(T^2) broadcast position-sort (keys unique) ----
    for (int t = tid; t < T; t += BS) {
        unsigned long long key = k[t];
        int pos = 0;
        for (int u = 0; u < T; ++u) pos += (k[u] > key) ? 1 : 0;
        sk[pos] = key;
    }
    __syncthreads();

    // ---- hist own chunk: pos(q) per pred via binary search ----
    const int start = chunk * CHSZ;
    const int end   = min(start + CHSZ, P);
    const float* pr = pred + (size_t)c * P * 7;
    for (int i = start + tid; i < end; i += BS) {
        unsigned long long kq =
            ((unsigned long long)__float_as_uint(pr[(size_t)i * 7 + 2]) << 32)
            | (unsigned)(P - 1 - i);
        int lo = 0;   // count of sorted-desc keys > kq (pads are 0, never > kq)
        #pragma unroll
        for (int step = 512; step > 0; step >>= 1)
            if (sk[lo + step - 1] > kq) lo += step;
        atomicAdd(&h[lo], 1);
    }
    __syncthreads();
    for (int j = tid; j < 1024; j += BS)
        if (h[j]) atomicAdd(&gHist[c * 1024 + j], h[j]);   // no-return
}

// ---------------- ap + mean: prefix over hist + closed-form + last-block ----
// Verbatim round-4 ap2m (passed absmax 0.0): gHist arrives via the kernel
// boundary; mean fold via the proven threadfence+ticket on 80 floats.
__global__ __launch_bounds__(BS) void ap2m_kernel(
        const int* __restrict__ sortT, const int* __restrict__ gHist,
        float* __restrict__ ap, unsigned int* __restrict__ doneCnt,
        float* __restrict__ out) {
    __shared__ int ha[1024];
    __shared__ int hb[1024];
    __shared__ float red[BS];
    const int c = blockIdx.x, tid = threadIdx.x;
    const int T = sortT[c];
    for (int j = tid; j < 1024; j += BS) ha[j] = gHist[c * 1024 + j];
    __syncthreads();
    int* src = ha; int* dst = hb;
    for (int o = 1; o < 1024; o <<= 1) {
        for (int j = tid; j < 1024; j += BS)
            dst[j] = src[j] + ((j >= o) ? src[j - o] : 0);
        __syncthreads();
        int* tmp = src; src = dst; dst = tmp;
    }
    float sum = 0.0f;
    for (int s = tid; s < T; s += BS) {
        int r = src[s] - 1;          // inclusive prefix minus self
        if (r >= 1) {
            float kf  = (float)(s + 1);
            float km  = (float)s;
            float ri  = __fdiv_rn(kf, 800.0f);
            float rim = __fdiv_rn(km, 800.0f);
            float pi  = __fdiv_rn(kf, (float)(r + 1));
            float pim = __fdiv_rn(km, (float)r);
            sum = __fadd_rn(sum,
                  __fmul_rn(__fmul_rn(__fsub_rn(ri, rim), __fadd_rn(pi, pim)), 0.5f));
        }
    }
    red[tid] = sum;
    __syncthreads();
    for (int s2 = BS / 2; s2 > 0; s2 >>= 1) {
        if (tid < s2) red[tid] = __fadd_rn(red[tid], red[tid + s2]);
        __syncthreads();
    }
    if (tid == 0) {
        ap[c] = red[0];
        __threadfence();                         // publish ap[c] device-wide
        unsigned int t = atomicAdd(doneCnt, 1u); // ticket
        if (t == C - 1) {                        // last block finishes the mean
            __threadfence();                     // acquire all ap[] writes
            float s = 0.0f;
            for (int c2 = 0; c2 < C; ++c2) s = __fadd_rn(s, ap[c2]);
            out[0] = __fdiv_rn(s, 80.0f);
        }
    }
}

extern "C" void kernel_launch(void* const* d_in, const int* in_sizes, int n_in,
                              void* d_out, int out_size, void* d_ws, size_t ws_size,
                              hipStream_t stream) {
    const float* pred = (const float*)d_in[0];   // [C, P, 7] f32
    const float* gt   = (const float*)d_in[1];   // [C, G, 7] f32
    float* out = (float*)d_out;

    // Workspace layout — 2,330,624 B total. Re-poisoned 0xAA each call —
    // gt_bin (incl. folded inits: gtKey, gHist, doneCnt) rewrites everything
    // read-before-write; sortT written by histf before ap2m reads it.
    char* ws = (char*)d_ws;
    int*                sortT      = (int*)               (ws + 0);         //     320 B
    float*              ap         = (float*)             (ws + 512);       //     320 B
    unsigned int*       doneCnt    = (unsigned int*)      (ws + 896);       //       4 B
    unsigned short*     gtCnt      = (unsigned short*)    (ws + 1024);      //  40960 B
    unsigned short*     gtOff      = (unsigned short*)    (ws + 41984);     //  40960 B
    unsigned short*     gtIdx      = (unsigned short*)    (ws + 82944);     // 128000 B
    float*              gtAbe      = (float*)             (ws + 210944);    // 256000 B
    float4*             gtBox      = (float4*)            (ws + 466944);    // 1.024 MB (16-aligned)
    unsigned long long* gtKey      = (unsigned long long*)(ws + 1490944);   // 512000 B
    int*                gHist      = (int*)               (ws + 2002944);   // 327680 B
    // end: 2330624 B

    const int M_BLK = (P + TPB - 1) / TPB;   // 15

    gt_bin_kernel<<<C, BS, 0, stream>>>(gt, gtCnt, gtOff, gtBox, gtAbe, gtIdx,
                                        gtKey, gHist, doneCnt);
    match7_kernel<<<dim3(M_BLK, C), BS, 0, stream>>>(pred, gtOff, gtCnt, gtBox,
                                                     gtAbe, gtIdx, gtKey);
    histf_kernel<<<dim3(HCH, C), BS, 0, stream>>>(pred, gtKey, gHist, sortT);
    ap2m_kernel<<<C, BS, 0, stream>>>(sortT, gHist, ap, doneCnt, out);
}